// Round 2
// baseline (2173.096 us; speedup 1.0000x reference)
//
#include <hip/hip_runtime.h>

typedef __attribute__((ext_vector_type(4))) float floatx4;
typedef __attribute__((ext_vector_type(8))) short short8;

// ---------- bf16 helpers (RNE) ----------
__device__ __forceinline__ float bf2f(unsigned short u) {
    union { unsigned int u; float f; } c; c.u = ((unsigned int)u) << 16; return c.f;
}
__device__ __forceinline__ unsigned short f2bf(float f) {
    union { float f; unsigned int u; } c; c.f = f;
    unsigned int r = c.u + 0x7FFFu + ((c.u >> 16) & 1u);
    return (unsigned short)(r >> 16);
}
__device__ __forceinline__ unsigned int pack2bf(float a, float b) {
    return (unsigned int)f2bf(a) | ((unsigned int)f2bf(b) << 16);
}

// ---------- async global->LDS, 16B per lane ----------
__device__ __forceinline__ void load_lds16(const unsigned short* g, unsigned short* l) {
    __builtin_amdgcn_global_load_lds(
        (__attribute__((address_space(1))) void*)(g),
        (__attribute__((address_space(3))) void*)(l), 16, 0, 0);
}

// ---------- CSR build ----------
__global__ void k_hist(const int* __restrict__ dst, const int* __restrict__ et,
                       int* __restrict__ deg, int* __restrict__ cnt4, int E) {
    int i = blockIdx.x * 256 + threadIdx.x;
    if (i < E) {
        int d = dst[i];
        atomicAdd(&deg[d], 1);
        atomicAdd(&cnt4[d * 4 + et[i]], 1);
    }
}

__global__ void k_scan(const int* __restrict__ deg, int* __restrict__ row_ptr,
                       int* __restrict__ cursor, int N) {
    __shared__ int sm[1024];
    __shared__ int carry_s;
    int tid = threadIdx.x;
    if (tid == 0) carry_s = 0;
    __syncthreads();
    int nch = (N + 1023) / 1024;
    for (int c = 0; c < nch; ++c) {
        int i = c * 1024 + tid;
        int v = (i < N) ? deg[i] : 0;
        sm[tid] = v;
        __syncthreads();
        for (int off = 1; off < 1024; off <<= 1) {
            int t = (tid >= off) ? sm[tid - off] : 0;
            __syncthreads();
            sm[tid] += t;
            __syncthreads();
        }
        int carry = carry_s;
        if (i < N) {
            int excl = carry + sm[tid] - v;
            row_ptr[i] = excl;
            cursor[i]  = excl;
        }
        __syncthreads();
        if (tid == 1023) carry_s = carry + sm[1023];
        __syncthreads();
    }
    if (tid == 0) row_ptr[N] = carry_s;
}

__global__ void k_scatter(const int* __restrict__ src, const int* __restrict__ dst,
                          const int* __restrict__ et, int* __restrict__ cursor,
                          int* __restrict__ edge_pk, int E) {
    int i = blockIdx.x * 256 + threadIdx.x;
    if (i < E) {
        int p = atomicAdd(&cursor[dst[i]], 1);
        edge_pk[p] = src[i] | (et[i] << 16);   // src < 65536 for N=50000
    }
}

// ---------- init h (bf16) into AH[:,128:256] ----------
__global__ void k_init_h(const float* __restrict__ feat, unsigned short* __restrict__ AH, int N) {
    int i = blockIdx.x * 256 + threadIdx.x;
    if (i < N * 128) {
        int v = i >> 7, d = i & 127;
        AH[(size_t)v * 256 + 128 + d] = f2bf(feat[i]);
    }
}

// ---------- weight prep: hi/lo bf16 split, n-major [Nout][K] ----------
__global__ void k_prep_wcat(const float* __restrict__ W, unsigned short* __restrict__ hi,
                            unsigned short* __restrict__ lo) {
    int i = blockIdx.x * 256 + threadIdx.x;   // 4*128*128 = 65536, flat = t*16384 + o*128 + d
    if (i < 65536) {
        int t = i >> 14, o = (i >> 7) & 127, d = i & 127;
        float w = W[i];
        unsigned short h = f2bf(w);
        int idx = o * 512 + t * 128 + d;      // [o][k], k = t*128+d
        hi[idx] = h;
        lo[idx] = f2bf(w - bf2f(h));
    }
}

__global__ void k_prep_wg(const float* __restrict__ Wih, const float* __restrict__ Whh,
                          unsigned short* __restrict__ hi, unsigned short* __restrict__ lo) {
    int i = blockIdx.x * 256 + threadIdx.x;   // 512*256
    if (i < 512 * 256) {
        int j = i >> 8, k = i & 255;          // j: out col, k over [a(128), h(128)]
        float w;
        if (j < 256)      w = (k < 128) ? Wih[j * 128 + k] : Whh[j * 128 + (k - 128)];
        else if (j < 384) w = (k < 128) ? Wih[j * 128 + k] : 0.f;   // i_n: a only
        else              w = (k < 128) ? 0.f : Whh[(j - 128) * 128 + (k - 128)]; // h_n
        unsigned short h = f2bf(w);
        hi[i] = h;
        lo[i] = f2bf(w - bf2f(h));
    }
}

// ---------- per-step: aggregate h[src] by (dst, etype): S[v][t*128+d] ----------
__global__ __launch_bounds__(256) void k_aggregate(
    const int* __restrict__ row_ptr, const int* __restrict__ edge_pk,
    const unsigned short* __restrict__ AH, unsigned short* __restrict__ S, int N)
{
    int wv = threadIdx.x >> 6;
    int lane = threadIdx.x & 63;
    int v = blockIdx.x * 4 + wv;
    if (v >= N) return;
    int beg = row_ptr[v], end = row_ptr[v + 1];
    float a0x = 0, a0y = 0, a1x = 0, a1y = 0, a2x = 0, a2y = 0, a3x = 0, a3y = 0;
    for (int e = beg; e < end; ++e) {
        int ep = edge_pk[e];                   // wave-uniform
        int s = ep & 0xFFFF;
        int t = ep >> 16;
        unsigned int hv = *(const unsigned int*)&AH[(size_t)s * 256 + 128 + lane * 2];
        float x0 = bf2f((unsigned short)(hv & 0xFFFF));
        float x1 = bf2f((unsigned short)(hv >> 16));
        if (t == 0)      { a0x += x0; a0y += x1; }
        else if (t == 1) { a1x += x0; a1y += x1; }
        else if (t == 2) { a2x += x0; a2y += x1; }
        else             { a3x += x0; a3y += x1; }
    }
    unsigned int* Sp = (unsigned int*)&S[(size_t)v * 512];
    Sp[lane]       = pack2bf(a0x, a0y);
    Sp[64 + lane]  = pack2bf(a1x, a1y);
    Sp[128 + lane] = pack2bf(a2x, a2y);
    Sp[192 + lane] = pack2bf(a3x, a3y);
}

// ---------- GEMM (etype transform): C[128,128] tile, 4 waves, hi+lo weight passes ----------
// out = bf16 a into AH[:,0:128], + per-etype-count bias.
__global__ __launch_bounds__(256) void k_gemm0(
    const unsigned short* __restrict__ A, int M,
    const unsigned short* __restrict__ Bhi, const unsigned short* __restrict__ Blo,
    unsigned short* __restrict__ outAH, const int* __restrict__ cnt4,
    const float* __restrict__ b_et)
{
    __shared__ __align__(16) unsigned short As[128 * 32];
    __shared__ __align__(16) unsigned short Bhs[128 * 32];
    __shared__ __align__(16) unsigned short Bls[128 * 32];
    const int tid  = threadIdx.x;
    const int lane = tid & 63;
    const int wv   = tid >> 6;
    const int wm   = (wv & 1) * 64;
    const int wn   = (wv >> 1) * 64;
    const int mBase = blockIdx.x * 128;
    const int srow = tid >> 2;
    const int sseg = (tid & 3) * 8;
    const int Ktot = 512;

    floatx4 acc[4][4];
#pragma unroll
    for (int i = 0; i < 4; ++i)
#pragma unroll
        for (int j = 0; j < 4; ++j) acc[i][j] = (floatx4){0.f, 0.f, 0.f, 0.f};

    for (int k0 = 0; k0 < Ktot; k0 += 32) {
        __syncthreads();
        {
            int r0 = mBase + srow;      if (r0 >= M) r0 = M - 1;
            int r1 = mBase + srow + 64; if (r1 >= M) r1 = M - 1;
            load_lds16(A + (size_t)r0 * 512 + k0 + sseg, &As[srow * 32 + sseg]);
            load_lds16(A + (size_t)r1 * 512 + k0 + sseg, &As[(srow + 64) * 32 + sseg]);
            const unsigned short* bh = Bhi + (size_t)srow * Ktot + k0 + sseg;
            load_lds16(bh,                     &Bhs[srow * 32 + sseg]);
            load_lds16(bh + (size_t)64 * Ktot, &Bhs[(srow + 64) * 32 + sseg]);
            const unsigned short* bl = Blo + (size_t)srow * Ktot + k0 + sseg;
            load_lds16(bl,                     &Bls[srow * 32 + sseg]);
            load_lds16(bl + (size_t)64 * Ktot, &Bls[(srow + 64) * 32 + sseg]);
        }
        __syncthreads();
        const int kof = (lane >> 4) * 8;
        const int mr  = lane & 15;
        short8 af[4], bh[4], bl[4];
#pragma unroll
        for (int i = 0; i < 4; ++i) af[i] = *(const short8*)&As[(wm + i * 16 + mr) * 32 + kof];
#pragma unroll
        for (int j = 0; j < 4; ++j) bh[j] = *(const short8*)&Bhs[(wn + j * 16 + mr) * 32 + kof];
#pragma unroll
        for (int j = 0; j < 4; ++j) bl[j] = *(const short8*)&Bls[(wn + j * 16 + mr) * 32 + kof];
#pragma unroll
        for (int i = 0; i < 4; ++i)
#pragma unroll
            for (int j = 0; j < 4; ++j) {
                acc[i][j] = __builtin_amdgcn_mfma_f32_16x16x32_bf16(af[i], bh[j], acc[i][j], 0, 0, 0);
                acc[i][j] = __builtin_amdgcn_mfma_f32_16x16x32_bf16(af[i], bl[j], acc[i][j], 0, 0, 0);
            }
    }

    const int mr4 = (lane >> 4) * 4;
    const int nc  = lane & 15;
#pragma unroll
    for (int i = 0; i < 4; ++i) {
#pragma unroll
        for (int r = 0; r < 4; ++r) {
            int row = mBase + wm + i * 16 + mr4 + r;
            if (row < M) {
                int cx = cnt4[row * 4 + 0], cy = cnt4[row * 4 + 1];
                int cz = cnt4[row * 4 + 2], cw = cnt4[row * 4 + 3];
#pragma unroll
                for (int j = 0; j < 4; ++j) {
                    int col = wn + j * 16 + nc;
                    float val = acc[i][j][r]
                        + (float)cx * b_et[col]       + (float)cy * b_et[128 + col]
                        + (float)cz * b_et[256 + col] + (float)cw * b_et[384 + col];
                    outAH[(size_t)row * 256 + col] = f2bf(val);
                }
            }
        }
    }
}

// ---------- fused gates-GEMM + GRU: M-tile 64, all 4 N-chunks (r,z,i_n,h_n) in regs ----------
// A = AH[:,0:256] (a|h, K=256). B = Wg[512][256] hi/lo. Writes h in-place into AH[:,128:256].
__global__ __launch_bounds__(256) void k_gemm_gru(
    unsigned short* __restrict__ AH, int M,
    const unsigned short* __restrict__ Bhi, const unsigned short* __restrict__ Blo,
    const float* __restrict__ b_ih, const float* __restrict__ b_hh)
{
    __shared__ __align__(16) unsigned short As[64 * 32];
    __shared__ __align__(16) unsigned short Bhs[512 * 32];
    __shared__ __align__(16) unsigned short Bls[512 * 32];
    const int tid  = threadIdx.x;
    const int lane = tid & 63;
    const int wv   = tid >> 6;
    const int wm   = (wv & 1) * 32;      // wave row offset (32 rows)
    const int wn   = (wv >> 1) * 64;     // wave col offset within 128-wide chunk
    const int mBase = blockIdx.x * 64;
    const int srow = tid >> 2;           // 0..63
    const int sseg = (tid & 3) * 8;

    floatx4 acc[4][2][4];                // [chunk r/z/i_n/h_n][row-tile][col-tile]
#pragma unroll
    for (int c = 0; c < 4; ++c)
#pragma unroll
        for (int i = 0; i < 2; ++i)
#pragma unroll
            for (int j = 0; j < 4; ++j) acc[c][i][j] = (floatx4){0.f, 0.f, 0.f, 0.f};

    for (int k0 = 0; k0 < 256; k0 += 32) {
        __syncthreads();
        {
            int r0 = mBase + srow; if (r0 >= M) r0 = M - 1;
            load_lds16(AH + (size_t)r0 * 256 + k0 + sseg, &As[srow * 32 + sseg]);
#pragma unroll
            for (int q = 0; q < 8; ++q) {
                int row = srow + q * 64;
                load_lds16(Bhi + (size_t)row * 256 + k0 + sseg, &Bhs[row * 32 + sseg]);
                load_lds16(Blo + (size_t)row * 256 + k0 + sseg, &Bls[row * 32 + sseg]);
            }
        }
        __syncthreads();
        const int kof = (lane >> 4) * 8;
        const int mr  = lane & 15;
        short8 af[2];
        af[0] = *(const short8*)&As[(wm + mr) * 32 + kof];
        af[1] = *(const short8*)&As[(wm + 16 + mr) * 32 + kof];
#pragma unroll
        for (int c = 0; c < 4; ++c) {
            short8 bh[4], bl[4];
#pragma unroll
            for (int j = 0; j < 4; ++j) {
                int br = c * 128 + wn + j * 16 + mr;
                bh[j] = *(const short8*)&Bhs[br * 32 + kof];
                bl[j] = *(const short8*)&Bls[br * 32 + kof];
            }
#pragma unroll
            for (int i = 0; i < 2; ++i)
#pragma unroll
                for (int j = 0; j < 4; ++j) {
                    acc[c][i][j] = __builtin_amdgcn_mfma_f32_16x16x32_bf16(af[i], bh[j], acc[c][i][j], 0, 0, 0);
                    acc[c][i][j] = __builtin_amdgcn_mfma_f32_16x16x32_bf16(af[i], bl[j], acc[c][i][j], 0, 0, 0);
                }
        }
    }

    const int mr4 = (lane >> 4) * 4;
    const int nc  = lane & 15;
#pragma unroll
    for (int i = 0; i < 2; ++i) {
#pragma unroll
        for (int r = 0; r < 4; ++r) {
            int row = mBase + wm + i * 16 + mr4 + r;
            if (row < M) {
#pragma unroll
                for (int j = 0; j < 4; ++j) {
                    int col = wn + j * 16 + nc;   // 0..127
                    float pre_r = acc[0][i][j][r] + b_ih[col]       + b_hh[col];
                    float pre_z = acc[1][i][j][r] + b_ih[128 + col] + b_hh[128 + col];
                    float i_n   = acc[2][i][j][r] + b_ih[256 + col];
                    float h_n   = acc[3][i][j][r] + b_hh[256 + col];
                    float rg = 1.f / (1.f + __expf(-pre_r));
                    float zg = 1.f / (1.f + __expf(-pre_z));
                    float n  = tanhf(i_n + rg * h_n);
                    size_t hidx = (size_t)row * 256 + 128 + col;
                    float h = bf2f(AH[hidx]);
                    AH[hidx] = f2bf((1.f - zg) * n + zg * h);
                }
            }
        }
    }
}

// ---------- readout: per-node dot + atomic per-graph sum, then sigmoid ----------
__global__ void k_dot(const unsigned short* __restrict__ AH, const int* __restrict__ gids,
                      const float* __restrict__ cls_w, float* __restrict__ gsum, int N) {
    int v = blockIdx.x * 4 + (threadIdx.x >> 6);
    int lane = threadIdx.x & 63;
    if (v >= N) return;
    unsigned int hv = *(const unsigned int*)&AH[(size_t)v * 256 + 128 + lane * 2];
    float x = bf2f((unsigned short)(hv & 0xFFFF)) * cls_w[lane * 2]
            + bf2f((unsigned short)(hv >> 16))    * cls_w[lane * 2 + 1];
#pragma unroll
    for (int off = 32; off > 0; off >>= 1) x += __shfl_down(x, off);
    if (lane == 0) atomicAdd(&gsum[gids[v]], x);
}

__global__ void k_final(const float* __restrict__ gsum, const float* __restrict__ cls_b,
                        float* __restrict__ out, int B) {
    int g = threadIdx.x;
    if (g < B) out[g] = 1.f / (1.f + expf(-(gsum[g] + cls_b[0])));
}

// ---------- host ----------
extern "C" void kernel_launch(void* const* d_in, const int* in_sizes, int n_in,
                              void* d_out, int out_size, void* d_ws, size_t ws_size,
                              hipStream_t stream) {
    const float* features = (const float*)d_in[0];
    const int*   src      = (const int*)d_in[1];
    const int*   dst      = (const int*)d_in[2];
    const int*   etype    = (const int*)d_in[3];
    const int*   gids     = (const int*)d_in[4];
    const float* W_etype  = (const float*)d_in[5];
    const float* b_etype  = (const float*)d_in[6];
    const float* W_ih     = (const float*)d_in[7];
    const float* W_hh     = (const float*)d_in[8];
    const float* b_ih     = (const float*)d_in[9];
    const float* b_hh     = (const float*)d_in[10];
    const float* cls_w    = (const float*)d_in[11];
    const float* cls_b    = (const float*)d_in[12];
    const int N = in_sizes[0] / 128;
    const int E = in_sizes[1];
    float* out = (float*)d_out;

    char* ws = (char*)d_ws;
    size_t off = 0;
    auto alloc = [&](size_t bytes) -> void* {
        off = (off + 255) & ~(size_t)255;
        void* p = ws + off;
        off += bytes;
        return p;
    };
    unsigned short* AH    = (unsigned short*)alloc((size_t)N * 256 * 2); // [a | h] bf16
    unsigned short* S     = (unsigned short*)alloc((size_t)N * 512 * 2);
    unsigned short* Wc_hi = (unsigned short*)alloc(128 * 512 * 2);
    unsigned short* Wc_lo = (unsigned short*)alloc(128 * 512 * 2);
    unsigned short* Wg_hi = (unsigned short*)alloc(512 * 256 * 2);
    unsigned short* Wg_lo = (unsigned short*)alloc(512 * 256 * 2);
    int* deg     = (int*)alloc((size_t)N * 4);
    int* row_ptr = (int*)alloc((size_t)(N + 1) * 4);
    int* cursor  = (int*)alloc((size_t)N * 4);
    int* cnt4    = (int*)alloc((size_t)N * 16);
    int* edge_pk = (int*)alloc((size_t)E * 4);
    float* gsum  = (float*)alloc(64 * 4);
    (void)ws_size; (void)n_in;

    hipMemsetAsync(deg, 0, (size_t)N * 4, stream);
    hipMemsetAsync(cnt4, 0, (size_t)N * 16, stream);
    hipMemsetAsync(gsum, 0, 64 * 4, stream);
    k_hist<<<(E + 255) / 256, 256, 0, stream>>>(dst, etype, deg, cnt4, E);
    k_scan<<<1, 1024, 0, stream>>>(deg, row_ptr, cursor, N);
    k_scatter<<<(E + 255) / 256, 256, 0, stream>>>(src, dst, etype, cursor, edge_pk, E);
    k_init_h<<<(N * 128 + 255) / 256, 256, 0, stream>>>(features, AH, N);
    k_prep_wcat<<<65536 / 256, 256, 0, stream>>>(W_etype, Wc_hi, Wc_lo);
    k_prep_wg<<<(512 * 256) / 256, 256, 0, stream>>>(W_ih, W_hh, Wg_hi, Wg_lo);

    const int mblocks128 = (N + 127) / 128;
    const int mblocks64  = (N + 63) / 64;
    for (int s = 0; s < 8; ++s) {
        k_aggregate<<<(N + 3) / 4, 256, 0, stream>>>(row_ptr, edge_pk, AH, S, N);
        k_gemm0<<<mblocks128, 256, 0, stream>>>(S, N, Wc_hi, Wc_lo, AH, cnt4, b_etype);
        k_gemm_gru<<<mblocks64, 256, 0, stream>>>(AH, N, Wg_hi, Wg_lo, b_ih, b_hh);
    }
    k_dot<<<(N + 3) / 4, 256, 0, stream>>>(AH, gids, cls_w, gsum, N);
    k_final<<<1, 64, 0, stream>>>(gsum, cls_b, out, out_size);
}

// Round 3
// 1537.449 us; speedup vs baseline: 1.4134x; 1.4134x over previous
//
#include <hip/hip_runtime.h>

typedef __attribute__((ext_vector_type(4))) float floatx4;
typedef __attribute__((ext_vector_type(8))) short short8;

// ---------- bf16 helpers (RNE) ----------
__device__ __forceinline__ float bf2f(unsigned short u) {
    union { unsigned int u; float f; } c; c.u = ((unsigned int)u) << 16; return c.f;
}
__device__ __forceinline__ unsigned short f2bf(float f) {
    union { float f; unsigned int u; } c; c.f = f;
    unsigned int r = c.u + 0x7FFFu + ((c.u >> 16) & 1u);
    return (unsigned short)(r >> 16);
}
__device__ __forceinline__ unsigned int pack2bf(float a, float b) {
    return (unsigned int)f2bf(a) | ((unsigned int)f2bf(b) << 16);
}

// ---------- async global->LDS, 16B per lane ----------
__device__ __forceinline__ void load_lds16(const unsigned short* g, unsigned short* l) {
    __builtin_amdgcn_global_load_lds(
        (__attribute__((address_space(1))) void*)(g),
        (__attribute__((address_space(3))) void*)(l), 16, 0, 0);
}

// ---------- CSR build ----------
__global__ void k_hist(const int* __restrict__ dst, const int* __restrict__ et,
                       int* __restrict__ deg, int* __restrict__ cnt4, int E) {
    int i = blockIdx.x * 256 + threadIdx.x;
    if (i < E) {
        int d = dst[i];
        atomicAdd(&deg[d], 1);
        atomicAdd(&cnt4[d * 4 + et[i]], 1);
    }
}

__global__ void k_scan(const int* __restrict__ deg, int* __restrict__ row_ptr,
                       int* __restrict__ cursor, int N) {
    __shared__ int sm[1024];
    __shared__ int carry_s;
    int tid = threadIdx.x;
    if (tid == 0) carry_s = 0;
    __syncthreads();
    int nch = (N + 1023) / 1024;
    for (int c = 0; c < nch; ++c) {
        int i = c * 1024 + tid;
        int v = (i < N) ? deg[i] : 0;
        sm[tid] = v;
        __syncthreads();
        for (int off = 1; off < 1024; off <<= 1) {
            int t = (tid >= off) ? sm[tid - off] : 0;
            __syncthreads();
            sm[tid] += t;
            __syncthreads();
        }
        int carry = carry_s;
        if (i < N) {
            int excl = carry + sm[tid] - v;
            row_ptr[i] = excl;
            cursor[i]  = excl;
        }
        __syncthreads();
        if (tid == 1023) carry_s = carry + sm[1023];
        __syncthreads();
    }
    if (tid == 0) row_ptr[N] = carry_s;
}

__global__ void k_scatter(const int* __restrict__ src, const int* __restrict__ dst,
                          const int* __restrict__ et, int* __restrict__ cursor,
                          int* __restrict__ edge_pk, int E) {
    int i = blockIdx.x * 256 + threadIdx.x;
    if (i < E) {
        int p = atomicAdd(&cursor[dst[i]], 1);
        edge_pk[p] = src[i] | (et[i] << 16);   // src < 65536 for N=50000
    }
}

// ---------- init h (bf16) into AH[:,128:256] ----------
__global__ void k_init_h(const float* __restrict__ feat, unsigned short* __restrict__ AH, int N) {
    int i = blockIdx.x * 256 + threadIdx.x;
    if (i < N * 128) {
        int v = i >> 7, d = i & 127;
        AH[(size_t)v * 256 + 128 + d] = f2bf(feat[i]);
    }
}

// ---------- weight prep: hi/lo bf16 split, n-major [Nout][K] ----------
__global__ void k_prep_wcat(const float* __restrict__ W, unsigned short* __restrict__ hi,
                            unsigned short* __restrict__ lo) {
    int i = blockIdx.x * 256 + threadIdx.x;   // 4*128*128 = 65536, flat = t*16384 + o*128 + d
    if (i < 65536) {
        int t = i >> 14, o = (i >> 7) & 127, d = i & 127;
        float w = W[i];
        unsigned short h = f2bf(w);
        int idx = o * 512 + t * 128 + d;      // [o][k], k = t*128+d
        hi[idx] = h;
        lo[idx] = f2bf(w - bf2f(h));
    }
}

__global__ void k_prep_wg(const float* __restrict__ Wih, const float* __restrict__ Whh,
                          unsigned short* __restrict__ hi, unsigned short* __restrict__ lo) {
    int i = blockIdx.x * 256 + threadIdx.x;   // 512*256
    if (i < 512 * 256) {
        int j = i >> 8, k = i & 255;          // j: out col, k over [a(128), h(128)]
        float w;
        if (j < 256)      w = (k < 128) ? Wih[j * 128 + k] : Whh[j * 128 + (k - 128)];
        else if (j < 384) w = (k < 128) ? Wih[j * 128 + k] : 0.f;   // i_n: a only
        else              w = (k < 128) ? 0.f : Whh[(j - 128) * 128 + (k - 128)]; // h_n
        unsigned short h = f2bf(w);
        hi[i] = h;
        lo[i] = f2bf(w - bf2f(h));
    }
}

// ---------- per-step: aggregate h[src] by (dst, etype): S[v][t*128+d] ----------
__global__ __launch_bounds__(256) void k_aggregate(
    const int* __restrict__ row_ptr, const int* __restrict__ edge_pk,
    const unsigned short* __restrict__ AH, unsigned short* __restrict__ S, int N)
{
    int wv = threadIdx.x >> 6;
    int lane = threadIdx.x & 63;
    int v = blockIdx.x * 4 + wv;
    if (v >= N) return;
    int beg = row_ptr[v], end = row_ptr[v + 1];
    float a0x = 0, a0y = 0, a1x = 0, a1y = 0, a2x = 0, a2y = 0, a3x = 0, a3y = 0;
    for (int e = beg; e < end; ++e) {
        int ep = edge_pk[e];                   // wave-uniform
        int s = ep & 0xFFFF;
        int t = ep >> 16;
        unsigned int hv = *(const unsigned int*)&AH[(size_t)s * 256 + 128 + lane * 2];
        float x0 = bf2f((unsigned short)(hv & 0xFFFF));
        float x1 = bf2f((unsigned short)(hv >> 16));
        if (t == 0)      { a0x += x0; a0y += x1; }
        else if (t == 1) { a1x += x0; a1y += x1; }
        else if (t == 2) { a2x += x0; a2y += x1; }
        else             { a3x += x0; a3y += x1; }
    }
    unsigned int* Sp = (unsigned int*)&S[(size_t)v * 512];
    Sp[lane]       = pack2bf(a0x, a0y);
    Sp[64 + lane]  = pack2bf(a1x, a1y);
    Sp[128 + lane] = pack2bf(a2x, a2y);
    Sp[192 + lane] = pack2bf(a3x, a3y);
}

// ---------- GEMM: C[128,128] tile, 4 waves, 16x16x32 bf16 MFMA, hi+lo weight passes ----------
// MODE 0: out = bf16 a into AH[:,0:128], + per-etype-count bias.  MODE 1: out = fp32 G[N,512].
template <int MODE>
__global__ __launch_bounds__(256) void k_gemm(
    const unsigned short* __restrict__ A, int lda, int Ktot, int M,
    const unsigned short* __restrict__ Bhi, const unsigned short* __restrict__ Blo,
    unsigned short* __restrict__ outAH, const int* __restrict__ cnt4,
    const float* __restrict__ b_et, float* __restrict__ G)
{
    __shared__ __align__(16) unsigned short As[128 * 32];
    __shared__ __align__(16) unsigned short Bhs[128 * 32];
    __shared__ __align__(16) unsigned short Bls[128 * 32];
    const int tid  = threadIdx.x;
    const int lane = tid & 63;
    const int wv   = tid >> 6;
    const int wm   = (wv & 1) * 64;
    const int wn   = (wv >> 1) * 64;
    const int mBase = blockIdx.x * 128;
    const int nBase = blockIdx.y * 128;
    const int srow = tid >> 2;         // 0..63
    const int sseg = (tid & 3) * 8;    // element offset within 32-wide row

    floatx4 acc[4][4];
#pragma unroll
    for (int i = 0; i < 4; ++i)
#pragma unroll
        for (int j = 0; j < 4; ++j) acc[i][j] = (floatx4){0.f, 0.f, 0.f, 0.f};

    for (int k0 = 0; k0 < Ktot; k0 += 32) {
        __syncthreads();
        {
            int r0 = mBase + srow;      if (r0 >= M) r0 = M - 1;
            int r1 = mBase + srow + 64; if (r1 >= M) r1 = M - 1;
            load_lds16(A + (size_t)r0 * lda + k0 + sseg, &As[srow * 32 + sseg]);
            load_lds16(A + (size_t)r1 * lda + k0 + sseg, &As[(srow + 64) * 32 + sseg]);
            const unsigned short* bh = Bhi + (size_t)(nBase + srow) * Ktot + k0 + sseg;
            load_lds16(bh,                     &Bhs[srow * 32 + sseg]);
            load_lds16(bh + (size_t)64 * Ktot, &Bhs[(srow + 64) * 32 + sseg]);
            const unsigned short* bl = Blo + (size_t)(nBase + srow) * Ktot + k0 + sseg;
            load_lds16(bl,                     &Bls[srow * 32 + sseg]);
            load_lds16(bl + (size_t)64 * Ktot, &Bls[(srow + 64) * 32 + sseg]);
        }
        __syncthreads();
        const int kof = (lane >> 4) * 8;
        const int mr  = lane & 15;
        short8 af[4], bh[4], bl[4];
#pragma unroll
        for (int i = 0; i < 4; ++i) af[i] = *(const short8*)&As[(wm + i * 16 + mr) * 32 + kof];
#pragma unroll
        for (int j = 0; j < 4; ++j) bh[j] = *(const short8*)&Bhs[(wn + j * 16 + mr) * 32 + kof];
#pragma unroll
        for (int j = 0; j < 4; ++j) bl[j] = *(const short8*)&Bls[(wn + j * 16 + mr) * 32 + kof];
#pragma unroll
        for (int i = 0; i < 4; ++i)
#pragma unroll
            for (int j = 0; j < 4; ++j) {
                acc[i][j] = __builtin_amdgcn_mfma_f32_16x16x32_bf16(af[i], bh[j], acc[i][j], 0, 0, 0);
                acc[i][j] = __builtin_amdgcn_mfma_f32_16x16x32_bf16(af[i], bl[j], acc[i][j], 0, 0, 0);
            }
    }

    const int mr4 = (lane >> 4) * 4;
    const int nc  = lane & 15;
#pragma unroll
    for (int i = 0; i < 4; ++i) {
#pragma unroll
        for (int r = 0; r < 4; ++r) {
            int row = mBase + wm + i * 16 + mr4 + r;
            if (row < M) {
                if (MODE == 0) {
                    int cx = cnt4[row * 4 + 0], cy = cnt4[row * 4 + 1];
                    int cz = cnt4[row * 4 + 2], cw = cnt4[row * 4 + 3];
#pragma unroll
                    for (int j = 0; j < 4; ++j) {
                        int col = wn + j * 16 + nc;
                        float val = acc[i][j][r]
                            + (float)cx * b_et[col]       + (float)cy * b_et[128 + col]
                            + (float)cz * b_et[256 + col] + (float)cw * b_et[384 + col];
                        outAH[(size_t)row * 256 + col] = f2bf(val);
                    }
                } else {
#pragma unroll
                    for (int j = 0; j < 4; ++j) {
                        int col = nBase + wn + j * 16 + nc;
                        G[(size_t)row * 512 + col] = acc[i][j][r];
                    }
                }
            }
        }
    }
}

// ---------- GRU elementwise ----------
__global__ void k_gru(const float* __restrict__ G, unsigned short* __restrict__ AH,
                      const float* __restrict__ b_ih, const float* __restrict__ b_hh, int N) {
    int i = blockIdx.x * 256 + threadIdx.x;
    if (i >= N * 128) return;
    int v = i >> 7, d = i & 127;
    const float* g = G + (size_t)v * 512;
    float pre_r = g[d]       + b_ih[d]       + b_hh[d];
    float pre_z = g[128 + d] + b_ih[128 + d] + b_hh[128 + d];
    float i_n   = g[256 + d] + b_ih[256 + d];
    float h_n   = g[384 + d] + b_hh[256 + d];
    float r = 1.f / (1.f + __expf(-pre_r));
    float z = 1.f / (1.f + __expf(-pre_z));
    float n = tanhf(i_n + r * h_n);
    size_t hidx = (size_t)v * 256 + 128 + d;
    float h = bf2f(AH[hidx]);
    AH[hidx] = f2bf((1.f - z) * n + z * h);
}

// ---------- readout stage 1: per-node classifier dot (no atomics) ----------
__global__ void k_dotv(const unsigned short* __restrict__ AH, const float* __restrict__ cls_w,
                       float* __restrict__ dotv, int N) {
    int v = blockIdx.x * 4 + (threadIdx.x >> 6);
    int lane = threadIdx.x & 63;
    if (v >= N) return;
    unsigned int hv = *(const unsigned int*)&AH[(size_t)v * 256 + 128 + lane * 2];
    float x = bf2f((unsigned short)(hv & 0xFFFF)) * cls_w[lane * 2]
            + bf2f((unsigned short)(hv >> 16))    * cls_w[lane * 2 + 1];
#pragma unroll
    for (int off = 32; off > 0; off >>= 1) x += __shfl_down(x, off);
    if (lane == 0) dotv[v] = x;
}

// ---------- readout stage 2: per-graph sum over sorted gids + sigmoid ----------
__global__ void k_gsum(const float* __restrict__ dotv, const int* __restrict__ gids,
                       const float* __restrict__ cls_b, float* __restrict__ out, int N) {
    int g = blockIdx.x;
    int t = threadIdx.x;   // 256
    int lo = 0, hi = N;
    while (lo < hi) { int m = (lo + hi) >> 1; if (gids[m] < g) lo = m + 1; else hi = m; }
    int s = lo;
    lo = 0; hi = N;
    while (lo < hi) { int m = (lo + hi) >> 1; if (gids[m] < g + 1) lo = m + 1; else hi = m; }
    int e = lo;
    float acc = 0.f;
    for (int v = s + t; v < e; v += 256) acc += dotv[v];
    __shared__ float red[256];
    red[t] = acc;
    __syncthreads();
    for (int off = 128; off > 0; off >>= 1) {
        if (t < off) red[t] += red[t + off];
        __syncthreads();
    }
    if (t == 0) out[g] = 1.f / (1.f + expf(-(red[0] + cls_b[0])));
}

// ---------- host ----------
extern "C" void kernel_launch(void* const* d_in, const int* in_sizes, int n_in,
                              void* d_out, int out_size, void* d_ws, size_t ws_size,
                              hipStream_t stream) {
    const float* features = (const float*)d_in[0];
    const int*   src      = (const int*)d_in[1];
    const int*   dst      = (const int*)d_in[2];
    const int*   etype    = (const int*)d_in[3];
    const int*   gids     = (const int*)d_in[4];
    const float* W_etype  = (const float*)d_in[5];
    const float* b_etype  = (const float*)d_in[6];
    const float* W_ih     = (const float*)d_in[7];
    const float* W_hh     = (const float*)d_in[8];
    const float* b_ih     = (const float*)d_in[9];
    const float* b_hh     = (const float*)d_in[10];
    const float* cls_w    = (const float*)d_in[11];
    const float* cls_b    = (const float*)d_in[12];
    const int N = in_sizes[0] / 128;
    const int E = in_sizes[1];
    float* out = (float*)d_out;

    char* ws = (char*)d_ws;
    size_t off = 0;
    auto alloc = [&](size_t bytes) -> void* {
        off = (off + 255) & ~(size_t)255;
        void* p = ws + off;
        off += bytes;
        return p;
    };
    unsigned short* AH    = (unsigned short*)alloc((size_t)N * 256 * 2); // [a | h] bf16
    unsigned short* S     = (unsigned short*)alloc((size_t)N * 512 * 2);
    float*          G     = (float*)alloc((size_t)N * 512 * 4);
    unsigned short* Wc_hi = (unsigned short*)alloc(128 * 512 * 2);
    unsigned short* Wc_lo = (unsigned short*)alloc(128 * 512 * 2);
    unsigned short* Wg_hi = (unsigned short*)alloc(512 * 256 * 2);
    unsigned short* Wg_lo = (unsigned short*)alloc(512 * 256 * 2);
    int* deg     = (int*)alloc((size_t)N * 4);
    int* row_ptr = (int*)alloc((size_t)(N + 1) * 4);
    int* cursor  = (int*)alloc((size_t)N * 4);
    int* cnt4    = (int*)alloc((size_t)N * 16);
    int* edge_pk = (int*)alloc((size_t)E * 4);
    float* dotv  = (float*)alloc((size_t)N * 4);
    (void)ws_size; (void)n_in;

    hipMemsetAsync(deg, 0, (size_t)N * 4, stream);
    hipMemsetAsync(cnt4, 0, (size_t)N * 16, stream);
    k_hist<<<(E + 255) / 256, 256, 0, stream>>>(dst, etype, deg, cnt4, E);
    k_scan<<<1, 1024, 0, stream>>>(deg, row_ptr, cursor, N);
    k_scatter<<<(E + 255) / 256, 256, 0, stream>>>(src, dst, etype, cursor, edge_pk, E);
    k_init_h<<<(N * 128 + 255) / 256, 256, 0, stream>>>(features, AH, N);
    k_prep_wcat<<<65536 / 256, 256, 0, stream>>>(W_etype, Wc_hi, Wc_lo);
    k_prep_wg<<<(512 * 256) / 256, 256, 0, stream>>>(W_ih, W_hh, Wg_hi, Wg_lo);

    const int mblocks = (N + 127) / 128;
    for (int s = 0; s < 8; ++s) {
        k_aggregate<<<(N + 3) / 4, 256, 0, stream>>>(row_ptr, edge_pk, AH, S, N);
        dim3 g1(mblocks, 1);
        k_gemm<0><<<g1, 256, 0, stream>>>(S, 512, 512, N, Wc_hi, Wc_lo, AH, cnt4, b_etype, nullptr);
        dim3 g2(mblocks, 4);
        k_gemm<1><<<g2, 256, 0, stream>>>(AH, 256, 256, N, Wg_hi, Wg_lo, nullptr, nullptr, nullptr, G);
        k_gru<<<(N * 128 + 255) / 256, 256, 0, stream>>>(G, AH, b_ih, b_hh, N);
    }
    k_dotv<<<(N + 3) / 4, 256, 0, stream>>>(AH, cls_w, dotv, N);
    k_gsum<<<out_size, 256, 0, stream>>>(dotv, gids, cls_b, out, N);
}

// Round 4
// 1443.324 us; speedup vs baseline: 1.5056x; 1.0652x over previous
//
#include <hip/hip_runtime.h>

typedef __attribute__((ext_vector_type(4))) float floatx4;
typedef __attribute__((ext_vector_type(8))) short short8;

// ---------- bf16 helpers (RNE) ----------
__device__ __forceinline__ float bf2f(unsigned short u) {
    union { unsigned int u; float f; } c; c.u = ((unsigned int)u) << 16; return c.f;
}
__device__ __forceinline__ unsigned short f2bf(float f) {
    union { float f; unsigned int u; } c; c.f = f;
    unsigned int r = c.u + 0x7FFFu + ((c.u >> 16) & 1u);
    return (unsigned short)(r >> 16);
}
__device__ __forceinline__ unsigned int pack2bf(float a, float b) {
    return (unsigned int)f2bf(a) | ((unsigned int)f2bf(b) << 16);
}

// ---------- async global->LDS, 16B per lane ----------
__device__ __forceinline__ void load_lds16(const unsigned short* g, unsigned short* l) {
    __builtin_amdgcn_global_load_lds(
        (__attribute__((address_space(1))) void*)(g),
        (__attribute__((address_space(3))) void*)(l), 16, 0, 0);
}

// ---------- CSR build ----------
__global__ void k_hist(const int* __restrict__ dst, const int* __restrict__ et,
                       int* __restrict__ deg, int* __restrict__ cnt4, int E) {
    int i = blockIdx.x * 256 + threadIdx.x;
    if (i < E) {
        int d = dst[i];
        atomicAdd(&deg[d], 1);
        atomicAdd(&cnt4[d * 4 + et[i]], 1);
    }
}

// hierarchical scan: block partials
__global__ void k_scan_blk(const int* __restrict__ deg, int* __restrict__ row_ptr,
                           int* __restrict__ bsum, int N) {
    __shared__ int sm[256];
    int b = blockIdx.x, t = threadIdx.x, i = b * 256 + t;
    int v = (i < N) ? deg[i] : 0;
    sm[t] = v;
    __syncthreads();
    for (int off = 1; off < 256; off <<= 1) {
        int x = (t >= off) ? sm[t - off] : 0;
        __syncthreads();
        sm[t] += x;
        __syncthreads();
    }
    if (i < N) row_ptr[i] = sm[t] - v;     // exclusive within block
    if (t == 255) bsum[b] = sm[255];
}

// scan of block sums (single block; nblocks <= 256)
__global__ void k_scan_top(int* __restrict__ bsum, int* __restrict__ boff,
                           int* __restrict__ row_ptr, int nblocks, int N) {
    __shared__ int sm[256];
    int t = threadIdx.x;
    int v = (t < nblocks) ? bsum[t] : 0;
    sm[t] = v;
    __syncthreads();
    for (int off = 1; off < 256; off <<= 1) {
        int x = (t >= off) ? sm[t - off] : 0;
        __syncthreads();
        sm[t] += x;
        __syncthreads();
    }
    if (t < nblocks) boff[t] = sm[t] - v;  // exclusive
    if (t == 255) row_ptr[N] = sm[255];
}

// add block offsets
__global__ void k_scan_add(int* __restrict__ row_ptr, int* __restrict__ cursor,
                           const int* __restrict__ boff, int N) {
    int i = blockIdx.x * 256 + threadIdx.x;
    if (i < N) {
        int r = row_ptr[i] + boff[blockIdx.x];
        row_ptr[i] = r;
        cursor[i]  = r;
    }
}

__global__ void k_scatter(const int* __restrict__ src, const int* __restrict__ dst,
                          const int* __restrict__ et, int* __restrict__ cursor,
                          int* __restrict__ edge_pk, int E) {
    int i = blockIdx.x * 256 + threadIdx.x;
    if (i < E) {
        int p = atomicAdd(&cursor[dst[i]], 1);
        edge_pk[p] = src[i] | (et[i] << 16);   // src < 65536 for N=50000
    }
}

// ---------- init h (bf16) into AH[:,128:256] ----------
__global__ void k_init_h(const float* __restrict__ feat, unsigned short* __restrict__ AH, int N) {
    int i = blockIdx.x * 256 + threadIdx.x;
    if (i < N * 128) {
        int v = i >> 7, d = i & 127;
        AH[(size_t)v * 256 + 128 + d] = f2bf(feat[i]);
    }
}

// ---------- weight prep: hi/lo bf16 split, n-major [Nout][K] ----------
__global__ void k_prep_wcat(const float* __restrict__ W, unsigned short* __restrict__ hi,
                            unsigned short* __restrict__ lo) {
    int i = blockIdx.x * 256 + threadIdx.x;   // 4*128*128 = 65536, flat = t*16384 + o*128 + d
    if (i < 65536) {
        int t = i >> 14, o = (i >> 7) & 127, d = i & 127;
        float w = W[i];
        unsigned short h = f2bf(w);
        int idx = o * 512 + t * 128 + d;      // [o][k], k = t*128+d
        hi[idx] = h;
        lo[idx] = f2bf(w - bf2f(h));
    }
}

__global__ void k_prep_wg(const float* __restrict__ Wih, const float* __restrict__ Whh,
                          unsigned short* __restrict__ hi, unsigned short* __restrict__ lo) {
    int i = blockIdx.x * 256 + threadIdx.x;   // 512*256
    if (i < 512 * 256) {
        int j = i >> 8, k = i & 255;          // j: out col, k over [a(128), h(128)]
        float w;
        if (j < 256)      w = (k < 128) ? Wih[j * 128 + k] : Whh[j * 128 + (k - 128)];
        else if (j < 384) w = (k < 128) ? Wih[j * 128 + k] : 0.f;   // i_n: a only
        else              w = (k < 128) ? 0.f : Whh[(j - 128) * 128 + (k - 128)]; // h_n
        unsigned short h = f2bf(w);
        hi[i] = h;
        lo[i] = f2bf(w - bf2f(h));
    }
}

// ---------- per-step: aggregate h[src] by (dst, etype): S[v][t*128+d] ----------
__global__ __launch_bounds__(256) void k_aggregate(
    const int* __restrict__ row_ptr, const int* __restrict__ edge_pk,
    const unsigned short* __restrict__ AH, unsigned short* __restrict__ S, int N)
{
    int wv = threadIdx.x >> 6;
    int lane = threadIdx.x & 63;
    int v = blockIdx.x * 4 + wv;
    if (v >= N) return;
    int beg = row_ptr[v], end = row_ptr[v + 1];
    float a0x = 0, a0y = 0, a1x = 0, a1y = 0, a2x = 0, a2y = 0, a3x = 0, a3y = 0;
    for (int e = beg; e < end; ++e) {
        int ep = edge_pk[e];                   // wave-uniform
        int s = ep & 0xFFFF;
        int t = ep >> 16;
        unsigned int hv = *(const unsigned int*)&AH[(size_t)s * 256 + 128 + lane * 2];
        float x0 = bf2f((unsigned short)(hv & 0xFFFF));
        float x1 = bf2f((unsigned short)(hv >> 16));
        if (t == 0)      { a0x += x0; a0y += x1; }
        else if (t == 1) { a1x += x0; a1y += x1; }
        else if (t == 2) { a2x += x0; a2y += x1; }
        else             { a3x += x0; a3y += x1; }
    }
    unsigned int* Sp = (unsigned int*)&S[(size_t)v * 512];
    Sp[lane]       = pack2bf(a0x, a0y);
    Sp[64 + lane]  = pack2bf(a1x, a1y);
    Sp[128 + lane] = pack2bf(a2x, a2y);
    Sp[192 + lane] = pack2bf(a3x, a3y);
}

// ---------- GEMM: C[128,128] tile, 4 waves, 16x16x32 bf16 MFMA, hi+lo weight passes ----------
// MODE 0: out = bf16 a into AH[:,0:128], + per-etype-count bias.  MODE 1: out = fp32 G[N,512].
template <int MODE>
__global__ __launch_bounds__(256) void k_gemm(
    const unsigned short* __restrict__ A, int lda, int Ktot, int M,
    const unsigned short* __restrict__ Bhi, const unsigned short* __restrict__ Blo,
    unsigned short* __restrict__ outAH, const int* __restrict__ cnt4,
    const float* __restrict__ b_et, float* __restrict__ G)
{
    __shared__ __align__(16) unsigned short As[128 * 32];
    __shared__ __align__(16) unsigned short Bhs[128 * 32];
    __shared__ __align__(16) unsigned short Bls[128 * 32];
    const int tid  = threadIdx.x;
    const int lane = tid & 63;
    const int wv   = tid >> 6;
    const int wm   = (wv & 1) * 64;
    const int wn   = (wv >> 1) * 64;
    const int mBase = blockIdx.x * 128;
    const int nBase = blockIdx.y * 128;
    const int srow = tid >> 2;         // 0..63
    const int sseg = (tid & 3) * 8;    // element offset within 32-wide row

    floatx4 acc[4][4];
#pragma unroll
    for (int i = 0; i < 4; ++i)
#pragma unroll
        for (int j = 0; j < 4; ++j) acc[i][j] = (floatx4){0.f, 0.f, 0.f, 0.f};

    for (int k0 = 0; k0 < Ktot; k0 += 32) {
        __syncthreads();
        {
            int r0 = mBase + srow;      if (r0 >= M) r0 = M - 1;
            int r1 = mBase + srow + 64; if (r1 >= M) r1 = M - 1;
            load_lds16(A + (size_t)r0 * lda + k0 + sseg, &As[srow * 32 + sseg]);
            load_lds16(A + (size_t)r1 * lda + k0 + sseg, &As[(srow + 64) * 32 + sseg]);
            const unsigned short* bh = Bhi + (size_t)(nBase + srow) * Ktot + k0 + sseg;
            load_lds16(bh,                     &Bhs[srow * 32 + sseg]);
            load_lds16(bh + (size_t)64 * Ktot, &Bhs[(srow + 64) * 32 + sseg]);
            const unsigned short* bl = Blo + (size_t)(nBase + srow) * Ktot + k0 + sseg;
            load_lds16(bl,                     &Bls[srow * 32 + sseg]);
            load_lds16(bl + (size_t)64 * Ktot, &Bls[(srow + 64) * 32 + sseg]);
        }
        __syncthreads();
        const int kof = (lane >> 4) * 8;
        const int mr  = lane & 15;
        short8 af[4], bh[4], bl[4];
#pragma unroll
        for (int i = 0; i < 4; ++i) af[i] = *(const short8*)&As[(wm + i * 16 + mr) * 32 + kof];
#pragma unroll
        for (int j = 0; j < 4; ++j) bh[j] = *(const short8*)&Bhs[(wn + j * 16 + mr) * 32 + kof];
#pragma unroll
        for (int j = 0; j < 4; ++j) bl[j] = *(const short8*)&Bls[(wn + j * 16 + mr) * 32 + kof];
#pragma unroll
        for (int i = 0; i < 4; ++i)
#pragma unroll
            for (int j = 0; j < 4; ++j) {
                acc[i][j] = __builtin_amdgcn_mfma_f32_16x16x32_bf16(af[i], bh[j], acc[i][j], 0, 0, 0);
                acc[i][j] = __builtin_amdgcn_mfma_f32_16x16x32_bf16(af[i], bl[j], acc[i][j], 0, 0, 0);
            }
    }

    const int mr4 = (lane >> 4) * 4;
    const int nc  = lane & 15;
#pragma unroll
    for (int i = 0; i < 4; ++i) {
#pragma unroll
        for (int r = 0; r < 4; ++r) {
            int row = mBase + wm + i * 16 + mr4 + r;
            if (row < M) {
                if (MODE == 0) {
                    int cx = cnt4[row * 4 + 0], cy = cnt4[row * 4 + 1];
                    int cz = cnt4[row * 4 + 2], cw = cnt4[row * 4 + 3];
#pragma unroll
                    for (int j = 0; j < 4; ++j) {
                        int col = wn + j * 16 + nc;
                        float val = acc[i][j][r]
                            + (float)cx * b_et[col]       + (float)cy * b_et[128 + col]
                            + (float)cz * b_et[256 + col] + (float)cw * b_et[384 + col];
                        outAH[(size_t)row * 256 + col] = f2bf(val);
                    }
                } else {
#pragma unroll
                    for (int j = 0; j < 4; ++j) {
                        int col = nBase + wn + j * 16 + nc;
                        G[(size_t)row * 512 + col] = acc[i][j][r];
                    }
                }
            }
        }
    }
}

// ---------- GRU elementwise ----------
__global__ void k_gru(const float* __restrict__ G, unsigned short* __restrict__ AH,
                      const float* __restrict__ b_ih, const float* __restrict__ b_hh, int N) {
    int i = blockIdx.x * 256 + threadIdx.x;
    if (i >= N * 128) return;
    int v = i >> 7, d = i & 127;
    const float* g = G + (size_t)v * 512;
    float pre_r = g[d]       + b_ih[d]       + b_hh[d];
    float pre_z = g[128 + d] + b_ih[128 + d] + b_hh[128 + d];
    float i_n   = g[256 + d] + b_ih[256 + d];
    float h_n   = g[384 + d] + b_hh[256 + d];
    float r = 1.f / (1.f + __expf(-pre_r));
    float z = 1.f / (1.f + __expf(-pre_z));
    float n = tanhf(i_n + r * h_n);
    size_t hidx = (size_t)v * 256 + 128 + d;
    float h = bf2f(AH[hidx]);
    AH[hidx] = f2bf((1.f - z) * n + z * h);
}

// ---------- readout stage 1: per-node classifier dot (no atomics) ----------
__global__ void k_dotv(const unsigned short* __restrict__ AH, const float* __restrict__ cls_w,
                       float* __restrict__ dotv, int N) {
    int v = blockIdx.x * 4 + (threadIdx.x >> 6);
    int lane = threadIdx.x & 63;
    if (v >= N) return;
    unsigned int hv = *(const unsigned int*)&AH[(size_t)v * 256 + 128 + lane * 2];
    float x = bf2f((unsigned short)(hv & 0xFFFF)) * cls_w[lane * 2]
            + bf2f((unsigned short)(hv >> 16))    * cls_w[lane * 2 + 1];
#pragma unroll
    for (int off = 32; off > 0; off >>= 1) x += __shfl_down(x, off);
    if (lane == 0) dotv[v] = x;
}

// ---------- readout stage 2: per-graph sum over sorted gids + sigmoid ----------
__global__ void k_gsum(const float* __restrict__ dotv, const int* __restrict__ gids,
                       const float* __restrict__ cls_b, float* __restrict__ out, int N) {
    int g = blockIdx.x;
    int t = threadIdx.x;   // 256
    int lo = 0, hi = N;
    while (lo < hi) { int m = (lo + hi) >> 1; if (gids[m] < g) lo = m + 1; else hi = m; }
    int s = lo;
    lo = 0; hi = N;
    while (lo < hi) { int m = (lo + hi) >> 1; if (gids[m] < g + 1) lo = m + 1; else hi = m; }
    int e = lo;
    float acc = 0.f;
    for (int v = s + t; v < e; v += 256) acc += dotv[v];
    __shared__ float red[256];
    red[t] = acc;
    __syncthreads();
    for (int off = 128; off > 0; off >>= 1) {
        if (t < off) red[t] += red[t + off];
        __syncthreads();
    }
    if (t == 0) out[g] = 1.f / (1.f + expf(-(red[0] + cls_b[0])));
}

// ---------- host ----------
extern "C" void kernel_launch(void* const* d_in, const int* in_sizes, int n_in,
                              void* d_out, int out_size, void* d_ws, size_t ws_size,
                              hipStream_t stream) {
    const float* features = (const float*)d_in[0];
    const int*   src      = (const int*)d_in[1];
    const int*   dst      = (const int*)d_in[2];
    const int*   etype    = (const int*)d_in[3];
    const int*   gids     = (const int*)d_in[4];
    const float* W_etype  = (const float*)d_in[5];
    const float* b_etype  = (const float*)d_in[6];
    const float* W_ih     = (const float*)d_in[7];
    const float* W_hh     = (const float*)d_in[8];
    const float* b_ih     = (const float*)d_in[9];
    const float* b_hh     = (const float*)d_in[10];
    const float* cls_w    = (const float*)d_in[11];
    const float* cls_b    = (const float*)d_in[12];
    const int N = in_sizes[0] / 128;
    const int E = in_sizes[1];
    float* out = (float*)d_out;

    char* ws = (char*)d_ws;
    size_t off = 0;
    auto alloc = [&](size_t bytes) -> void* {
        off = (off + 255) & ~(size_t)255;
        void* p = ws + off;
        off += bytes;
        return p;
    };
    unsigned short* AH    = (unsigned short*)alloc((size_t)N * 256 * 2); // [a | h] bf16
    unsigned short* S     = (unsigned short*)alloc((size_t)N * 512 * 2);
    float*          G     = (float*)alloc((size_t)N * 512 * 4);
    unsigned short* Wc_hi = (unsigned short*)alloc(128 * 512 * 2);
    unsigned short* Wc_lo = (unsigned short*)alloc(128 * 512 * 2);
    unsigned short* Wg_hi = (unsigned short*)alloc(512 * 256 * 2);
    unsigned short* Wg_lo = (unsigned short*)alloc(512 * 256 * 2);
    int* deg     = (int*)alloc((size_t)N * 4);
    int* row_ptr = (int*)alloc((size_t)(N + 1) * 4);
    int* cursor  = (int*)alloc((size_t)N * 4);
    int* cnt4    = (int*)alloc((size_t)N * 16);
    int* edge_pk = (int*)alloc((size_t)E * 4);
    float* dotv  = (float*)alloc((size_t)N * 4);
    int* bsum    = (int*)alloc(256 * 4);
    int* boff    = (int*)alloc(256 * 4);
    (void)ws_size; (void)n_in;

    const int nscan = (N + 255) / 256;   // 196 for N=50000 (must be <= 256)
    hipMemsetAsync(deg, 0, (size_t)N * 4, stream);
    hipMemsetAsync(cnt4, 0, (size_t)N * 16, stream);
    k_hist<<<(E + 255) / 256, 256, 0, stream>>>(dst, etype, deg, cnt4, E);
    k_scan_blk<<<nscan, 256, 0, stream>>>(deg, row_ptr, bsum, N);
    k_scan_top<<<1, 256, 0, stream>>>(bsum, boff, row_ptr, nscan, N);
    k_scan_add<<<nscan, 256, 0, stream>>>(row_ptr, cursor, boff, N);
    k_scatter<<<(E + 255) / 256, 256, 0, stream>>>(src, dst, etype, cursor, edge_pk, E);
    k_init_h<<<(N * 128 + 255) / 256, 256, 0, stream>>>(features, AH, N);
    k_prep_wcat<<<65536 / 256, 256, 0, stream>>>(W_etype, Wc_hi, Wc_lo);
    k_prep_wg<<<(512 * 256) / 256, 256, 0, stream>>>(W_ih, W_hh, Wg_hi, Wg_lo);

    const int mblocks = (N + 127) / 128;
    for (int s = 0; s < 8; ++s) {
        k_aggregate<<<(N + 3) / 4, 256, 0, stream>>>(row_ptr, edge_pk, AH, S, N);
        dim3 g1(mblocks, 1);
        k_gemm<0><<<g1, 256, 0, stream>>>(S, 512, 512, N, Wc_hi, Wc_lo, AH, cnt4, b_etype, nullptr);
        dim3 g2(mblocks, 4);
        k_gemm<1><<<g2, 256, 0, stream>>>(AH, 256, 256, N, Wg_hi, Wg_lo, nullptr, nullptr, nullptr, G);
        k_gru<<<(N * 128 + 255) / 256, 256, 0, stream>>>(G, AH, b_ih, b_hh, N);
    }
    k_dotv<<<(N + 3) / 4, 256, 0, stream>>>(AH, cls_w, dotv, N);
    k_gsum<<<out_size, 256, 0, stream>>>(dotv, gids, cls_b, out, N);
}

// Round 5
// 1267.211 us; speedup vs baseline: 1.7149x; 1.1390x over previous
//
#include <hip/hip_runtime.h>

typedef __attribute__((ext_vector_type(4))) float floatx4;
typedef __attribute__((ext_vector_type(8))) short short8;

// ---------- bf16 helpers (RNE) ----------
__device__ __forceinline__ float bf2f(unsigned short u) {
    union { unsigned int u; float f; } c; c.u = ((unsigned int)u) << 16; return c.f;
}
__device__ __forceinline__ unsigned short f2bf(float f) {
    union { float f; unsigned int u; } c; c.f = f;
    unsigned int r = c.u + 0x7FFFu + ((c.u >> 16) & 1u);
    return (unsigned short)(r >> 16);
}
__device__ __forceinline__ unsigned int pack2bf(float a, float b) {
    return (unsigned int)f2bf(a) | ((unsigned int)f2bf(b) << 16);
}

// ---------- async global->LDS, 16B per lane ----------
__device__ __forceinline__ void load_lds16(const unsigned short* g, unsigned short* l) {
    __builtin_amdgcn_global_load_lds(
        (__attribute__((address_space(1))) void*)(g),
        (__attribute__((address_space(3))) void*)(l), 16, 0, 0);
}

// ---------- CSR build ----------
__global__ void k_hist(const int* __restrict__ dst, const int* __restrict__ et,
                       int* __restrict__ deg, int* __restrict__ cnt4, int E) {
    int i = blockIdx.x * 256 + threadIdx.x;
    if (i < E) {
        int d = dst[i];
        atomicAdd(&deg[d], 1);
        atomicAdd(&cnt4[d * 4 + et[i]], 1);
    }
}

// hierarchical scan: block partials
__global__ void k_scan_blk(const int* __restrict__ deg, int* __restrict__ row_ptr,
                           int* __restrict__ bsum, int N) {
    __shared__ int sm[256];
    int b = blockIdx.x, t = threadIdx.x, i = b * 256 + t;
    int v = (i < N) ? deg[i] : 0;
    sm[t] = v;
    __syncthreads();
    for (int off = 1; off < 256; off <<= 1) {
        int x = (t >= off) ? sm[t - off] : 0;
        __syncthreads();
        sm[t] += x;
        __syncthreads();
    }
    if (i < N) row_ptr[i] = sm[t] - v;     // exclusive within block
    if (t == 255) bsum[b] = sm[255];
}

// scan of block sums (single block; nblocks <= 256)
__global__ void k_scan_top(int* __restrict__ bsum, int* __restrict__ boff,
                           int* __restrict__ row_ptr, int nblocks, int N) {
    __shared__ int sm[256];
    int t = threadIdx.x;
    int v = (t < nblocks) ? bsum[t] : 0;
    sm[t] = v;
    __syncthreads();
    for (int off = 1; off < 256; off <<= 1) {
        int x = (t >= off) ? sm[t - off] : 0;
        __syncthreads();
        sm[t] += x;
        __syncthreads();
    }
    if (t < nblocks) boff[t] = sm[t] - v;  // exclusive
    if (t == 255) row_ptr[N] = sm[255];
}

// add block offsets
__global__ void k_scan_add(int* __restrict__ row_ptr, int* __restrict__ cursor,
                           const int* __restrict__ boff, int N) {
    int i = blockIdx.x * 256 + threadIdx.x;
    if (i < N) {
        int r = row_ptr[i] + boff[blockIdx.x];
        row_ptr[i] = r;
        cursor[i]  = r;
    }
}

__global__ void k_scatter(const int* __restrict__ src, const int* __restrict__ dst,
                          const int* __restrict__ et, int* __restrict__ cursor,
                          int* __restrict__ edge_pk, int E) {
    int i = blockIdx.x * 256 + threadIdx.x;
    if (i < E) {
        int p = atomicAdd(&cursor[dst[i]], 1);
        edge_pk[p] = src[i] | (et[i] << 16);   // src < 65536 for N=50000
    }
}

// ---------- init h (bf16) into AH[:,128:256] ----------
__global__ void k_init_h(const float* __restrict__ feat, unsigned short* __restrict__ AH, int N) {
    int i = blockIdx.x * 256 + threadIdx.x;
    if (i < N * 128) {
        int v = i >> 7, d = i & 127;
        AH[(size_t)v * 256 + 128 + d] = f2bf(feat[i]);
    }
}

// ---------- weight prep: hi/lo bf16 split, n-major [Nout][K] ----------
__global__ void k_prep_wcat(const float* __restrict__ W, unsigned short* __restrict__ hi,
                            unsigned short* __restrict__ lo) {
    int i = blockIdx.x * 256 + threadIdx.x;   // 4*128*128 = 65536, flat = t*16384 + o*128 + d
    if (i < 65536) {
        int t = i >> 14, o = (i >> 7) & 127, d = i & 127;
        float w = W[i];
        unsigned short h = f2bf(w);
        int idx = o * 512 + t * 128 + d;      // [o][k], k = t*128+d
        hi[idx] = h;
        lo[idx] = f2bf(w - bf2f(h));
    }
}

__global__ void k_prep_wg(const float* __restrict__ Wih, const float* __restrict__ Whh,
                          unsigned short* __restrict__ hi, unsigned short* __restrict__ lo) {
    int i = blockIdx.x * 256 + threadIdx.x;   // 512*256
    if (i < 512 * 256) {
        int j = i >> 8, k = i & 255;          // j: out col, k over [a(128), h(128)]
        float w;
        if (j < 256)      w = (k < 128) ? Wih[j * 128 + k] : Whh[j * 128 + (k - 128)];
        else if (j < 384) w = (k < 128) ? Wih[j * 128 + k] : 0.f;   // i_n: a only
        else              w = (k < 128) ? 0.f : Whh[(j - 128) * 128 + (k - 128)]; // h_n
        unsigned short h = f2bf(w);
        hi[i] = h;
        lo[i] = f2bf(w - bf2f(h));
    }
}

// ---------- per-step: aggregate h[src] by (dst, etype): S[v][t*128+d] ----------
// 4-way edge unroll: 4 independent gathers in flight per wave (latency-bound fix).
// Accumulation order per etype bucket is IDENTICAL to the serial loop (bit-exact).
__global__ __launch_bounds__(256) void k_aggregate(
    const int* __restrict__ row_ptr, const int* __restrict__ edge_pk,
    const unsigned short* __restrict__ AH, unsigned short* __restrict__ S, int N)
{
    int wv = threadIdx.x >> 6;
    int lane = threadIdx.x & 63;
    int v = blockIdx.x * 4 + wv;
    if (v >= N) return;
    int beg = row_ptr[v], end = row_ptr[v + 1];
    float a0x = 0, a0y = 0, a1x = 0, a1y = 0, a2x = 0, a2y = 0, a3x = 0, a3y = 0;

    const unsigned short* hbase = AH + 128 + lane * 2;

#define ACC_EDGE(EP, HV)                                            \
    {                                                               \
        int t_ = (EP) >> 16;                                        \
        float x0_ = bf2f((unsigned short)((HV) & 0xFFFF));          \
        float x1_ = bf2f((unsigned short)((HV) >> 16));             \
        if (t_ == 0)      { a0x += x0_; a0y += x1_; }               \
        else if (t_ == 1) { a1x += x0_; a1y += x1_; }               \
        else if (t_ == 2) { a2x += x0_; a2y += x1_; }               \
        else              { a3x += x0_; a3y += x1_; }               \
    }

    int e = beg;
    for (; e + 4 <= end; e += 4) {
        int ep0 = edge_pk[e];
        int ep1 = edge_pk[e + 1];
        int ep2 = edge_pk[e + 2];
        int ep3 = edge_pk[e + 3];
        unsigned int hv0 = *(const unsigned int*)(hbase + (size_t)(ep0 & 0xFFFF) * 256);
        unsigned int hv1 = *(const unsigned int*)(hbase + (size_t)(ep1 & 0xFFFF) * 256);
        unsigned int hv2 = *(const unsigned int*)(hbase + (size_t)(ep2 & 0xFFFF) * 256);
        unsigned int hv3 = *(const unsigned int*)(hbase + (size_t)(ep3 & 0xFFFF) * 256);
        ACC_EDGE(ep0, hv0);
        ACC_EDGE(ep1, hv1);
        ACC_EDGE(ep2, hv2);
        ACC_EDGE(ep3, hv3);
    }
    for (; e < end; ++e) {
        int ep = edge_pk[e];
        unsigned int hv = *(const unsigned int*)(hbase + (size_t)(ep & 0xFFFF) * 256);
        ACC_EDGE(ep, hv);
    }
#undef ACC_EDGE

    unsigned int* Sp = (unsigned int*)&S[(size_t)v * 512];
    Sp[lane]       = pack2bf(a0x, a0y);
    Sp[64 + lane]  = pack2bf(a1x, a1y);
    Sp[128 + lane] = pack2bf(a2x, a2y);
    Sp[192 + lane] = pack2bf(a3x, a3y);
}

// ---------- GEMM: C[128,128] tile, 4 waves, 16x16x32 bf16 MFMA, hi+lo weight passes ----------
// MODE 0: out = bf16 a into AH[:,0:128], + per-etype-count bias.  MODE 1: out = fp32 G[N,512].
template <int MODE>
__global__ __launch_bounds__(256) void k_gemm(
    const unsigned short* __restrict__ A, int lda, int Ktot, int M,
    const unsigned short* __restrict__ Bhi, const unsigned short* __restrict__ Blo,
    unsigned short* __restrict__ outAH, const int* __restrict__ cnt4,
    const float* __restrict__ b_et, float* __restrict__ G)
{
    __shared__ __align__(16) unsigned short As[128 * 32];
    __shared__ __align__(16) unsigned short Bhs[128 * 32];
    __shared__ __align__(16) unsigned short Bls[128 * 32];
    const int tid  = threadIdx.x;
    const int lane = tid & 63;
    const int wv   = tid >> 6;
    const int wm   = (wv & 1) * 64;
    const int wn   = (wv >> 1) * 64;
    const int mBase = blockIdx.x * 128;
    const int nBase = blockIdx.y * 128;
    const int srow = tid >> 2;         // 0..63
    const int sseg = (tid & 3) * 8;    // element offset within 32-wide row

    floatx4 acc[4][4];
#pragma unroll
    for (int i = 0; i < 4; ++i)
#pragma unroll
        for (int j = 0; j < 4; ++j) acc[i][j] = (floatx4){0.f, 0.f, 0.f, 0.f};

    for (int k0 = 0; k0 < Ktot; k0 += 32) {
        __syncthreads();
        {
            int r0 = mBase + srow;      if (r0 >= M) r0 = M - 1;
            int r1 = mBase + srow + 64; if (r1 >= M) r1 = M - 1;
            load_lds16(A + (size_t)r0 * lda + k0 + sseg, &As[srow * 32 + sseg]);
            load_lds16(A + (size_t)r1 * lda + k0 + sseg, &As[(srow + 64) * 32 + sseg]);
            const unsigned short* bh = Bhi + (size_t)(nBase + srow) * Ktot + k0 + sseg;
            load_lds16(bh,                     &Bhs[srow * 32 + sseg]);
            load_lds16(bh + (size_t)64 * Ktot, &Bhs[(srow + 64) * 32 + sseg]);
            const unsigned short* bl = Blo + (size_t)(nBase + srow) * Ktot + k0 + sseg;
            load_lds16(bl,                     &Bls[srow * 32 + sseg]);
            load_lds16(bl + (size_t)64 * Ktot, &Bls[(srow + 64) * 32 + sseg]);
        }
        __syncthreads();
        const int kof = (lane >> 4) * 8;
        const int mr  = lane & 15;
        short8 af[4], bh[4], bl[4];
#pragma unroll
        for (int i = 0; i < 4; ++i) af[i] = *(const short8*)&As[(wm + i * 16 + mr) * 32 + kof];
#pragma unroll
        for (int j = 0; j < 4; ++j) bh[j] = *(const short8*)&Bhs[(wn + j * 16 + mr) * 32 + kof];
#pragma unroll
        for (int j = 0; j < 4; ++j) bl[j] = *(const short8*)&Bls[(wn + j * 16 + mr) * 32 + kof];
#pragma unroll
        for (int i = 0; i < 4; ++i)
#pragma unroll
            for (int j = 0; j < 4; ++j) {
                acc[i][j] = __builtin_amdgcn_mfma_f32_16x16x32_bf16(af[i], bh[j], acc[i][j], 0, 0, 0);
                acc[i][j] = __builtin_amdgcn_mfma_f32_16x16x32_bf16(af[i], bl[j], acc[i][j], 0, 0, 0);
            }
    }

    const int mr4 = (lane >> 4) * 4;
    const int nc  = lane & 15;
#pragma unroll
    for (int i = 0; i < 4; ++i) {
#pragma unroll
        for (int r = 0; r < 4; ++r) {
            int row = mBase + wm + i * 16 + mr4 + r;
            if (row < M) {
                if (MODE == 0) {
                    int cx = cnt4[row * 4 + 0], cy = cnt4[row * 4 + 1];
                    int cz = cnt4[row * 4 + 2], cw = cnt4[row * 4 + 3];
#pragma unroll
                    for (int j = 0; j < 4; ++j) {
                        int col = wn + j * 16 + nc;
                        float val = acc[i][j][r]
                            + (float)cx * b_et[col]       + (float)cy * b_et[128 + col]
                            + (float)cz * b_et[256 + col] + (float)cw * b_et[384 + col];
                        outAH[(size_t)row * 256 + col] = f2bf(val);
                    }
                } else {
#pragma unroll
                    for (int j = 0; j < 4; ++j) {
                        int col = nBase + wn + j * 16 + nc;
                        G[(size_t)row * 512 + col] = acc[i][j][r];
                    }
                }
            }
        }
    }
}

// ---------- GRU elementwise ----------
__global__ void k_gru(const float* __restrict__ G, unsigned short* __restrict__ AH,
                      const float* __restrict__ b_ih, const float* __restrict__ b_hh, int N) {
    int i = blockIdx.x * 256 + threadIdx.x;
    if (i >= N * 128) return;
    int v = i >> 7, d = i & 127;
    const float* g = G + (size_t)v * 512;
    float pre_r = g[d]       + b_ih[d]       + b_hh[d];
    float pre_z = g[128 + d] + b_ih[128 + d] + b_hh[128 + d];
    float i_n   = g[256 + d] + b_ih[256 + d];
    float h_n   = g[384 + d] + b_hh[256 + d];
    float r = 1.f / (1.f + __expf(-pre_r));
    float z = 1.f / (1.f + __expf(-pre_z));
    float n = tanhf(i_n + r * h_n);
    size_t hidx = (size_t)v * 256 + 128 + d;
    float h = bf2f(AH[hidx]);
    AH[hidx] = f2bf((1.f - z) * n + z * h);
}

// ---------- readout stage 1: per-node classifier dot (no atomics) ----------
__global__ void k_dotv(const unsigned short* __restrict__ AH, const float* __restrict__ cls_w,
                       float* __restrict__ dotv, int N) {
    int v = blockIdx.x * 4 + (threadIdx.x >> 6);
    int lane = threadIdx.x & 63;
    if (v >= N) return;
    unsigned int hv = *(const unsigned int*)&AH[(size_t)v * 256 + 128 + lane * 2];
    float x = bf2f((unsigned short)(hv & 0xFFFF)) * cls_w[lane * 2]
            + bf2f((unsigned short)(hv >> 16))    * cls_w[lane * 2 + 1];
#pragma unroll
    for (int off = 32; off > 0; off >>= 1) x += __shfl_down(x, off);
    if (lane == 0) dotv[v] = x;
}

// ---------- readout stage 2: per-graph sum over sorted gids + sigmoid ----------
__global__ void k_gsum(const float* __restrict__ dotv, const int* __restrict__ gids,
                       const float* __restrict__ cls_b, float* __restrict__ out, int N) {
    int g = blockIdx.x;
    int t = threadIdx.x;   // 256
    int lo = 0, hi = N;
    while (lo < hi) { int m = (lo + hi) >> 1; if (gids[m] < g) lo = m + 1; else hi = m; }
    int s = lo;
    lo = 0; hi = N;
    while (lo < hi) { int m = (lo + hi) >> 1; if (gids[m] < g + 1) lo = m + 1; else hi = m; }
    int e = lo;
    float acc = 0.f;
    for (int v = s + t; v < e; v += 256) acc += dotv[v];
    __shared__ float red[256];
    red[t] = acc;
    __syncthreads();
    for (int off = 128; off > 0; off >>= 1) {
        if (t < off) red[t] += red[t + off];
        __syncthreads();
    }
    if (t == 0) out[g] = 1.f / (1.f + expf(-(red[0] + cls_b[0])));
}

// ---------- host ----------
extern "C" void kernel_launch(void* const* d_in, const int* in_sizes, int n_in,
                              void* d_out, int out_size, void* d_ws, size_t ws_size,
                              hipStream_t stream) {
    const float* features = (const float*)d_in[0];
    const int*   src      = (const int*)d_in[1];
    const int*   dst      = (const int*)d_in[2];
    const int*   etype    = (const int*)d_in[3];
    const int*   gids     = (const int*)d_in[4];
    const float* W_etype  = (const float*)d_in[5];
    const float* b_etype  = (const float*)d_in[6];
    const float* W_ih     = (const float*)d_in[7];
    const float* W_hh     = (const float*)d_in[8];
    const float* b_ih     = (const float*)d_in[9];
    const float* b_hh     = (const float*)d_in[10];
    const float* cls_w    = (const float*)d_in[11];
    const float* cls_b    = (const float*)d_in[12];
    const int N = in_sizes[0] / 128;
    const int E = in_sizes[1];
    float* out = (float*)d_out;

    char* ws = (char*)d_ws;
    size_t off = 0;
    auto alloc = [&](size_t bytes) -> void* {
        off = (off + 255) & ~(size_t)255;
        void* p = ws + off;
        off += bytes;
        return p;
    };
    unsigned short* AH    = (unsigned short*)alloc((size_t)N * 256 * 2); // [a | h] bf16
    unsigned short* S     = (unsigned short*)alloc((size_t)N * 512 * 2);
    float*          G     = (float*)alloc((size_t)N * 512 * 4);
    unsigned short* Wc_hi = (unsigned short*)alloc(128 * 512 * 2);
    unsigned short* Wc_lo = (unsigned short*)alloc(128 * 512 * 2);
    unsigned short* Wg_hi = (unsigned short*)alloc(512 * 256 * 2);
    unsigned short* Wg_lo = (unsigned short*)alloc(512 * 256 * 2);
    int* deg     = (int*)alloc((size_t)N * 4);
    int* row_ptr = (int*)alloc((size_t)(N + 1) * 4);
    int* cursor  = (int*)alloc((size_t)N * 4);
    int* cnt4    = (int*)alloc((size_t)N * 16);
    int* edge_pk = (int*)alloc((size_t)E * 4);
    float* dotv  = (float*)alloc((size_t)N * 4);
    int* bsum    = (int*)alloc(256 * 4);
    int* boff    = (int*)alloc(256 * 4);
    (void)ws_size; (void)n_in;

    const int nscan = (N + 255) / 256;   // 196 for N=50000 (must be <= 256)
    hipMemsetAsync(deg, 0, (size_t)N * 4, stream);
    hipMemsetAsync(cnt4, 0, (size_t)N * 16, stream);
    k_hist<<<(E + 255) / 256, 256, 0, stream>>>(dst, etype, deg, cnt4, E);
    k_scan_blk<<<nscan, 256, 0, stream>>>(deg, row_ptr, bsum, N);
    k_scan_top<<<1, 256, 0, stream>>>(bsum, boff, row_ptr, nscan, N);
    k_scan_add<<<nscan, 256, 0, stream>>>(row_ptr, cursor, boff, N);
    k_scatter<<<(E + 255) / 256, 256, 0, stream>>>(src, dst, etype, cursor, edge_pk, E);
    k_init_h<<<(N * 128 + 255) / 256, 256, 0, stream>>>(features, AH, N);
    k_prep_wcat<<<65536 / 256, 256, 0, stream>>>(W_etype, Wc_hi, Wc_lo);
    k_prep_wg<<<(512 * 256) / 256, 256, 0, stream>>>(W_ih, W_hh, Wg_hi, Wg_lo);

    const int mblocks = (N + 127) / 128;
    for (int s = 0; s < 8; ++s) {
        k_aggregate<<<(N + 3) / 4, 256, 0, stream>>>(row_ptr, edge_pk, AH, S, N);
        dim3 g1(mblocks, 1);
        k_gemm<0><<<g1, 256, 0, stream>>>(S, 512, 512, N, Wc_hi, Wc_lo, AH, cnt4, b_etype, nullptr);
        dim3 g2(mblocks, 4);
        k_gemm<1><<<g2, 256, 0, stream>>>(AH, 256, 256, N, Wg_hi, Wg_lo, nullptr, nullptr, nullptr, G);
        k_gru<<<(N * 128 + 255) / 256, 256, 0, stream>>>(G, AH, b_ih, b_hh, N);
    }
    k_dotv<<<(N + 3) / 4, 256, 0, stream>>>(AH, cls_w, dotv, N);
    k_gsum<<<out_size, 256, 0, stream>>>(dotv, gids, cls_b, out, N);
}